// Round 8
// baseline (564.406 us; speedup 1.0000x reference)
//
#include <hip/hip_runtime.h>
#include <hip/hip_bf16.h>

#define SLOPE 0.2f
#define EPS_GN 1e-5f
#define APITCH 136  // LDS row pitch in bf16 elems (272 B): 16B-aligned, breaks power-of-2 bank aliasing
#define NBUCK 391   // ceil(100000/256) dst-buckets of 256 nodes

typedef __attribute__((ext_vector_type(8))) short bfrag;   // 8 bf16 = 4 VGPR (MFMA A/B operand)
typedef __attribute__((ext_vector_type(4))) float ffrag;   // 4 fp32 accumulator

__device__ __forceinline__ float lrelu(float v) { return v > 0.f ? v : SLOPE * v; }
__device__ __forceinline__ unsigned int flipf(float x) {
    unsigned int u = __float_as_uint(x);
    return (u & 0x80000000u) ? ~u : (u | 0x80000000u);
}
__device__ __forceinline__ float unflipf(unsigned int u) {
    return __uint_as_float((u & 0x80000000u) ? (u & 0x7fffffffu) : ~u);
}
__device__ __forceinline__ short f2bs(float v) {
    __hip_bfloat16 h = __float2bfloat16(v);
    return *reinterpret_cast<short*>(&h);
}
__device__ __forceinline__ float blo(unsigned int u) { return __uint_as_float(u << 16); }
__device__ __forceinline__ float bhi(unsigned int u) { return __uint_as_float(u & 0xffff0000u); }

// ---------------- init scratch: nzero words of 0, then nff words of 0xFF ------
__global__ void init_kernel(unsigned int* __restrict__ p, int nzero, int nff) {
    int i = blockIdx.x * 256 + threadIdx.x;
    if (i < nzero) p[i] = 0u;
    else if (i < nzero + nff) p[i] = 0xFFFFFFFFu;
}

// ------- weight prep: WT1b[c][k] = bf16((w1@enc_w)[c,k]), bc1 = w1@enc_b ------
__global__ void prep_weights(const float* __restrict__ enc_w,
                             const float* __restrict__ enc_b,
                             const float* __restrict__ w1,
                             const float* __restrict__ w2,
                             unsigned short* __restrict__ WT1b,
                             unsigned short* __restrict__ WT2b,
                             float* __restrict__ bc1, float* __restrict__ bc2) {
    int c = blockIdx.x;   // 128 blocks (output channel)
    int k = threadIdx.x;  // 128 threads (input channel)
    __shared__ float w1row[128];
    w1row[k] = w1[c * 128 + k];
    __syncthreads();
    float acc = 0.f;
    for (int j = 0; j < 128; ++j)
        acc = fmaf(w1row[j], enc_w[j * 128 + k], acc);
    WT1b[c * 128 + k] = (unsigned short)f2bs(acc);
    WT2b[c * 128 + k] = (unsigned short)f2bs(w2[c * 128 + k]);
    if (k == 0) {
        float b = 0.f;
        for (int j = 0; j < 128; ++j) b += w1row[j] * enc_b[j];
        bc1[c] = b;
        bc2[c] = 0.f;
    }
}

// ============ CSR build: two-level bucketed counting sort =====================
// bucket b = dst >> 8 (256 nodes/bucket). Staged word = (src<<8)|(dst&255).

__global__ void __launch_bounds__(256) bucket_hist(const int* __restrict__ ei,
                                                   int* __restrict__ bhist, int E, int N) {
    __shared__ int h[NBUCK];
    for (int i = threadIdx.x; i < NBUCK; i += 256) h[i] = 0;
    __syncthreads();
    int base = blockIdx.x * 4096;
#pragma unroll
    for (int s = 0; s < 16; ++s) {
        int e = base + s * 256 + threadIdx.x;
        if (e < E + N) {
            int dst = (e < E) ? ei[E + e] : (e - E);
            atomicAdd(&h[dst >> 8], 1);
        }
    }
    __syncthreads();
    for (int i = threadIdx.x; i < NBUCK; i += 256)
        if (h[i]) atomicAdd(&bhist[i], h[i]);
}

__global__ void bucket_scan(const int* __restrict__ bhist,
                            int* __restrict__ bbase, int* __restrict__ bcur) {
    __shared__ int sh[512];
    int t = threadIdx.x;  // 512 threads
    int v = (t < NBUCK) ? bhist[t] : 0;
    sh[t] = v;
    __syncthreads();
    for (int off = 1; off < 512; off <<= 1) {
        int add = (t >= off) ? sh[t - off] : 0;
        __syncthreads();
        sh[t] += add;
        __syncthreads();
    }
    if (t < NBUCK) {
        bbase[t] = sh[t] - v;
        bcur[t] = sh[t] - v;
    }
}

__global__ void __launch_bounds__(256) bucket_scatter(const int* __restrict__ ei,
                                                      int* __restrict__ bcur,
                                                      unsigned int* __restrict__ staging,
                                                      int E, int N) {
    __shared__ int h[NBUCK];
    __shared__ int lb[NBUCK];
    for (int i = threadIdx.x; i < NBUCK; i += 256) h[i] = 0;
    __syncthreads();
    int base = blockIdx.x * 4096;
    int srcv[16], dstv[16];
#pragma unroll
    for (int s = 0; s < 16; ++s) {
        int e = base + s * 256 + threadIdx.x;
        srcv[s] = -1;
        if (e < E + N) {
            srcv[s] = (e < E) ? ei[e] : (e - E);
            dstv[s] = (e < E) ? ei[E + e] : (e - E);
            atomicAdd(&h[dstv[s] >> 8], 1);
        }
    }
    __syncthreads();
    for (int i = threadIdx.x; i < NBUCK; i += 256) {
        int c = h[i];
        lb[i] = c ? atomicAdd(&bcur[i], c) : 0;
        h[i] = 0;  // reuse as within-block cursor
    }
    __syncthreads();
#pragma unroll
    for (int s = 0; s < 16; ++s) {
        if (srcv[s] >= 0) {
            int b = dstv[s] >> 8;
            int slot = atomicAdd(&h[b], 1);
            staging[lb[b] + slot] = ((unsigned int)srcv[s] << 8) | (unsigned int)(dstv[s] & 255);
        }
    }
}

// fused: per-bucket degree hist -> LDS exclusive scan -> rowp -> CSR scatter.
__global__ void __launch_bounds__(256) bucket_finalize(
    const unsigned int* __restrict__ staging,
    const int* __restrict__ bbase, const int* __restrict__ bcur,
    int* __restrict__ rowp, int* __restrict__ esrc, int N, int Etot) {
    int b = blockIdx.x, t = threadIdx.x;
    __shared__ int h[256], sc[256];
    h[t] = 0;
    __syncthreads();
    int s0 = bbase[b], s1 = bcur[b];
    for (int j = s0 + t; j < s1; j += 256)
        atomicAdd(&h[staging[j] & 255], 1);
    __syncthreads();
    int d = h[t];
    sc[t] = d;
    __syncthreads();
    for (int off = 1; off < 256; off <<= 1) {
        int add = (t >= off) ? sc[t - off] : 0;
        __syncthreads();
        sc[t] += add;
        __syncthreads();
    }
    int excl = s0 + sc[t] - d;
    int node = b * 256 + t;
    if (node < N) rowp[node] = excl;
    if (b == 0 && t == 0) rowp[N] = Etot;
    __syncthreads();
    h[t] = excl;  // within-bucket cursors
    __syncthreads();
    for (int j = s0 + t; j < s1; j += 256) {
        unsigned int p = staging[j];
        int pos = atomicAdd(&h[p & 255], 1);
        esrc[pos] = (int)(p >> 8);
    }
}

// --------- MFMA GEMM: H[n][128] (bf16) = act(A[n][128]) @ WT^T + bc; + scores --
__global__ void __launch_bounds__(256) gemm_mfma(
    const void* __restrict__ Ain, const unsigned short* __restrict__ WTb,
    const float* __restrict__ bias, const float* __restrict__ att_src,
    const float* __restrict__ att_dst, const int* __restrict__ batch,
    const float* __restrict__ Ac, const float* __restrict__ Bc,
    unsigned int* __restrict__ H, float* __restrict__ ssrc, float* __restrict__ sdst, int N) {
    __shared__ short Bsh[128 * APITCH];  // [c][k] bf16
    __shared__ short Ash[64 * APITCH];   // [node][k] bf16 (reused for C)
    __shared__ float asrc_s[128], adst_s[128], bias_s[128];
    int tid = threadIdx.x;
    int base = blockIdx.x * 64;

    for (int idx = tid; idx < 2048; idx += 256) {
        int c = idx >> 4, k8 = (idx & 15) * 8;
        uint4 wv = ((const uint4*)WTb)[idx];
        *(uint4*)&Bsh[c * APITCH + k8] = wv;
    }
    if (Ac == nullptr) {
        const float* A = (const float*)Ain;
        for (int idx = tid; idx < 2048; idx += 256) {
            int nl = idx >> 5, k4 = (idx & 31) * 4;
            int node = base + nl;
            float4 v = make_float4(0.f, 0.f, 0.f, 0.f);
            if (node < N) v = ((const float4*)A)[node * 32 + (idx & 31)];
            *(short4*)&Ash[nl * APITCH + k4] =
                make_short4(f2bs(v.x), f2bs(v.y), f2bs(v.z), f2bs(v.w));
        }
    } else {
        const uint4* A4 = (const uint4*)Ain;
        for (int idx = tid; idx < 1024; idx += 256) {
            int nl = idx >> 4, u4 = idx & 15, k8 = u4 * 8;
            int node = base + nl;
            short o[8] = {0, 0, 0, 0, 0, 0, 0, 0};
            if (node < N) {
                uint4 hb = A4[node * 16 + u4];
                int g = batch[node];
                float4 a0 = *(const float4*)&Ac[g * 128 + k8];
                float4 a1 = *(const float4*)&Ac[g * 128 + k8 + 4];
                float4 b0 = *(const float4*)&Bc[g * 128 + k8];
                float4 b1 = *(const float4*)&Bc[g * 128 + k8 + 4];
                o[0] = f2bs(fmaf(blo(hb.x), a0.x, b0.x));
                o[1] = f2bs(fmaf(bhi(hb.x), a0.y, b0.y));
                o[2] = f2bs(fmaf(blo(hb.y), a0.z, b0.z));
                o[3] = f2bs(fmaf(bhi(hb.y), a0.w, b0.w));
                o[4] = f2bs(fmaf(blo(hb.z), a1.x, b1.x));
                o[5] = f2bs(fmaf(bhi(hb.z), a1.y, b1.y));
                o[6] = f2bs(fmaf(blo(hb.w), a1.z, b1.z));
                o[7] = f2bs(fmaf(bhi(hb.w), a1.w, b1.w));
            }
            *(bfrag*)&Ash[nl * APITCH + k8] = *(bfrag*)o;
        }
    }
    if (tid < 128) {
        asrc_s[tid] = att_src[tid];
        adst_s[tid] = att_dst[tid];
        bias_s[tid] = bias[tid];
    }
    __syncthreads();

    int w = tid >> 6, lane = tid & 63, col = lane & 15, quad = lane >> 4;
    int rowBase = w * 16;

    bfrag afr[4];
#pragma unroll
    for (int s = 0; s < 4; ++s)
        afr[s] = *(const bfrag*)&Ash[(rowBase + col) * APITCH + s * 32 + quad * 8];

    ffrag acc[8];
#pragma unroll
    for (int t = 0; t < 8; ++t) acc[t] = (ffrag){0.f, 0.f, 0.f, 0.f};

#pragma unroll
    for (int t = 0; t < 8; ++t) {
#pragma unroll
        for (int s = 0; s < 4; ++s) {
            bfrag bfr = *(const bfrag*)&Bsh[(t * 16 + col) * APITCH + s * 32 + quad * 8];
            acc[t] = __builtin_amdgcn_mfma_f32_16x16x32_bf16(afr[s], bfr, acc[t], 0, 0, 0);
        }
    }

#pragma unroll
    for (int t = 0; t < 8; ++t) {
        int ch = t * 16 + col;
        float bv = bias_s[ch];
#pragma unroll
        for (int r = 0; r < 4; ++r)
            Ash[(rowBase + quad * 4 + r) * APITCH + ch] = f2bs(acc[t][r] + bv);
    }
    __syncthreads();

    float2 av = make_float2(asrc_s[lane * 2], asrc_s[lane * 2 + 1]);
    float2 dv = make_float2(adst_s[lane * 2], adst_s[lane * 2 + 1]);
    for (int r = 0; r < 16; ++r) {
        int node = base + rowBase + r;
        unsigned int hb = *(const unsigned int*)&Ash[(rowBase + r) * APITCH + lane * 2];
        float hx = blo(hb);
        float hy = bhi(hb);
        float vs = hx * av.x + hy * av.y;
        float vd = hx * dv.x + hy * dv.y;
#pragma unroll
        for (int off = 8; off; off >>= 1) {
            vs += __shfl_xor(vs, off, 16);
            vd += __shfl_xor(vd, off, 16);
        }
        if (node < N) {
            H[node * 64 + lane] = hb;
            if ((lane & 15) == 0) {
                int h = lane >> 4;
                ssrc[node * 4 + h] = vs;
                sdst[node * 4 + h] = vd;
            }
        }
    }
}

// ------- aggregation: single-pass softmax num+den; ONE WAVE PER NODE ----------
// (round-5 form: max MLP across 100k waves; fusion attempts regress — R7)
// wave = 4 edge-slots x 16 lanes; lane owns 8 contiguous channels (one head).
__global__ void __launch_bounds__(256) agg_kernel(
    const int* __restrict__ row, const int* __restrict__ esrc,
    const float* __restrict__ ssrc, const float* __restrict__ sdst,
    const uint4* __restrict__ H4, const float* __restrict__ bias,
    uint4* __restrict__ out, int N) {
    int n = (blockIdx.x * 256 + threadIdx.x) >> 6;
    int lane = threadIdx.x & 63;
    if (n >= N) return;
    int slot = lane >> 4, li = lane & 15, head = li >> 2;
    int beg = row[n], end = row[n + 1];
    float sdh = sdst[n * 4 + head];

    float num[8] = {0.f, 0.f, 0.f, 0.f, 0.f, 0.f, 0.f, 0.f};
    float den = 0.f;
    for (int e = beg + slot; e < end; e += 4) {
        int s = esrc[e];
        float al = __expf(lrelu(ssrc[s * 4 + head] + sdh));
        uint4 hb = H4[s * 16 + li];
        den += al;
        num[0] = fmaf(al, blo(hb.x), num[0]);
        num[1] = fmaf(al, bhi(hb.x), num[1]);
        num[2] = fmaf(al, blo(hb.y), num[2]);
        num[3] = fmaf(al, bhi(hb.y), num[3]);
        num[4] = fmaf(al, blo(hb.z), num[4]);
        num[5] = fmaf(al, bhi(hb.z), num[5]);
        num[6] = fmaf(al, blo(hb.w), num[6]);
        num[7] = fmaf(al, bhi(hb.w), num[7]);
    }
    den += __shfl_xor(den, 16);
    den += __shfl_xor(den, 32);
#pragma unroll
    for (int j = 0; j < 8; ++j) {
        num[j] += __shfl_xor(num[j], 16);
        num[j] += __shfl_xor(num[j], 32);
    }
    if (slot == 0) {
        float rh = 1.f / den;
        int c0 = li * 8;
        unsigned int o[4];
#pragma unroll
        for (int p = 0; p < 4; ++p) {
            float v0 = fmaf(num[2 * p], rh, bias[c0 + 2 * p]);
            float v1 = fmaf(num[2 * p + 1], rh, bias[c0 + 2 * p + 1]);
            v0 = v0 > 0.f ? v0 : __expf(v0) - 1.f;  // ELU
            v1 = v1 > 0.f ? v1 : __expf(v1) - 1.f;
            o[p] = ((unsigned int)(unsigned short)f2bs(v0)) |
                   (((unsigned int)(unsigned short)f2bs(v1)) << 16);
        }
        out[n * 16 + li] = make_uint4(o[0], o[1], o[2], o[3]);
    }
}

// ------- GraphNorm stats (+ raw max/min pool for layer 2), vectorized ---------
// block = 256 thr / 64 nodes; thread owns fixed channel-octet u4=t&15 and rows
// rg, rg+16, rg+32, rg+48 (rg=t>>4). 2 group-sets per 64-node window (sorted
// batch). Register partials -> padded-LDS tree reduce -> few global atomics.
template <int POOL>
__global__ void __launch_bounds__(256) stats_kernel(
    const uint4* __restrict__ X4, const int* __restrict__ batch,
    float* __restrict__ gsum, float* __restrict__ gsq,
    unsigned int* __restrict__ rawmax, unsigned int* __restrict__ rawmin, int N) {
    __shared__ float red[16][16][9];  // [rowgroup][u4][ch(+pad)]
    int t = threadIdx.x, u4 = t & 15, rg = t >> 4;
    int base = blockIdx.x * 64;
    int g0 = batch[base];
    int g1 = batch[min(base + 63, N - 1)];

    float s[2][8] = {}, q[2][8] = {};
    float mx[2][8], mn[2][8];
#pragma unroll
    for (int st = 0; st < 2; ++st)
#pragma unroll
        for (int p = 0; p < 8; ++p) { mx[st][p] = -3e38f; mn[st][p] = 3e38f; }

#pragma unroll
    for (int rr = 0; rr < 4; ++rr) {
        int node = base + rg + rr * 16;
        if (node < N) {
            uint4 hb = X4[node * 16 + u4];
            int st = (batch[node] != g0) ? 1 : 0;
            float vv[8] = {blo(hb.x), bhi(hb.x), blo(hb.y), bhi(hb.y),
                           blo(hb.z), bhi(hb.z), blo(hb.w), bhi(hb.w)};
#pragma unroll
            for (int p = 0; p < 8; ++p) {
                s[st][p] += vv[p];
                q[st][p] += vv[p] * vv[p];
                if (POOL) {
                    mx[st][p] = fmaxf(mx[st][p], vv[p]);
                    mn[st][p] = fminf(mn[st][p], vv[p]);
                }
            }
        }
    }

    int c = t, uu = t >> 3, ch = t & 7;  // reducer mapping (threads 0..127)
    float rs[2], rq[2], rmx[2], rmn[2];
    int nset = (g1 != g0) ? 2 : 1;
    for (int st = 0; st < nset; ++st) {
        // sum
#pragma unroll
        for (int p = 0; p < 8; ++p) red[rg][u4][p] = s[st][p];
        __syncthreads();
        if (t < 128) {
            float a = 0.f;
            for (int r2 = 0; r2 < 16; ++r2) a += red[r2][uu][ch];
            rs[st] = a;
        }
        __syncthreads();
        // sumsq
#pragma unroll
        for (int p = 0; p < 8; ++p) red[rg][u4][p] = q[st][p];
        __syncthreads();
        if (t < 128) {
            float a = 0.f;
            for (int r2 = 0; r2 < 16; ++r2) a += red[r2][uu][ch];
            rq[st] = a;
        }
        __syncthreads();
        if (POOL) {
#pragma unroll
            for (int p = 0; p < 8; ++p) red[rg][u4][p] = mx[st][p];
            __syncthreads();
            if (t < 128) {
                float a = -3e38f;
                for (int r2 = 0; r2 < 16; ++r2) a = fmaxf(a, red[r2][uu][ch]);
                rmx[st] = a;
            }
            __syncthreads();
#pragma unroll
            for (int p = 0; p < 8; ++p) red[rg][u4][p] = mn[st][p];
            __syncthreads();
            if (t < 128) {
                float a = 3e38f;
                for (int r2 = 0; r2 < 16; ++r2) a = fminf(a, red[r2][uu][ch]);
                rmn[st] = a;
            }
            __syncthreads();
        }
    }
    if (t < 128) {
        for (int st = 0; st < nset; ++st) {
            int g = (st == 0) ? g0 : g1;
            atomicAdd(&gsum[g * 128 + c], rs[st]);
            atomicAdd(&gsq[g * 128 + c], rq[st]);
            if (POOL) {
                if (rmx[st] > -2e38f) atomicMax(&rawmax[g * 128 + c], flipf(rmx[st]));
                if (rmn[st] < 2e38f) atomicMin(&rawmin[g * 128 + c], flipf(rmn[st]));
            }
        }
    }
}

// ---------------- GraphNorm coefficients (group count via binary search) ------
__global__ void norm_coef(const float* __restrict__ gsum, const float* __restrict__ gsq,
                          const int* __restrict__ batch, int N,
                          const float* __restrict__ w, const float* __restrict__ b,
                          const float* __restrict__ ms,
                          float* __restrict__ Ac, float* __restrict__ Bc) {
    __shared__ float cnt_s;
    int g = blockIdx.x, c = threadIdx.x;
    if (c == 0) {
        int lo = 0, hi = N;
        while (lo < hi) { int m = (lo + hi) >> 1; if (batch[m] < g) lo = m + 1; else hi = m; }
        int lo2 = lo, hi2 = N;
        while (lo2 < hi2) { int m = (lo2 + hi2) >> 1; if (batch[m] < g + 1) lo2 = m + 1; else hi2 = m; }
        cnt_s = (float)(lo2 - lo);
    }
    __syncthreads();
    int i = g * 128 + c;
    float cntv = cnt_s;
    if (cntv < 0.5f) { Ac[i] = 0.f; Bc[i] = 0.f; return; }
    float mean = gsum[i] / cntv;
    float msv = ms[c];
    float var = gsq[i] / cntv - msv * (2.f - msv) * mean * mean;
    var = fmaxf(var, 0.f);
    float inv = rsqrtf(var + EPS_GN);
    float wv = w[c];
    Ac[i] = wv * inv;
    Bc[i] = b[c] - msv * mean * wv * inv;
}

// -------- FC with fused normalize-of-pooled-extrema --------------------------
// GraphNorm is affine per (g,c): monotone, so segment_max(norm(x)) =
// Ac>=0 ? Ac*max(x)+Bc : Ac*min(x)+Bc.
__global__ void fc_kernel(const unsigned int* __restrict__ rawmax,
                          const unsigned int* __restrict__ rawmin,
                          const float* __restrict__ Ac, const float* __restrict__ Bc,
                          const float* __restrict__ fcw,
                          const float* __restrict__ fcb,
                          float* __restrict__ out) {
    int g = blockIdx.x, o = threadIdx.x;  // 64 x 64
    __shared__ float p[128];
#pragma unroll
    for (int h = 0; h < 2; ++h) {
        int c = o + h * 64;
        float a = Ac[g * 128 + c], bb = Bc[g * 128 + c];
        float M = unflipf(rawmax[g * 128 + c]);
        float m = unflipf(rawmin[g * 128 + c]);
        p[c] = (a >= 0.f) ? fmaf(a, M, bb) : fmaf(a, m, bb);
    }
    __syncthreads();
    float acc = fcb[o];
    for (int k = 0; k < 128; ++k)
        acc = fmaf(p[k], fcw[o * 128 + k], acc);
    out[g * 64 + o] = acc;
}

extern "C" void kernel_launch(void* const* d_in, const int* in_sizes, int n_in,
                              void* d_out, int out_size, void* d_ws, size_t ws_size,
                              hipStream_t stream) {
    const float* x     = (const float*)d_in[0];
    const int* ei      = (const int*)d_in[1];
    const int* batch   = (const int*)d_in[2];
    const float* enc_w = (const float*)d_in[3];
    const float* enc_b = (const float*)d_in[4];
    const float* w1    = (const float*)d_in[5];
    const float* as1   = (const float*)d_in[6];
    const float* ad1   = (const float*)d_in[7];
    const float* b1    = (const float*)d_in[8];
    const float* n1w   = (const float*)d_in[9];
    const float* n1b   = (const float*)d_in[10];
    const float* n1ms  = (const float*)d_in[11];
    const float* w2    = (const float*)d_in[12];
    const float* as2   = (const float*)d_in[13];
    const float* ad2   = (const float*)d_in[14];
    const float* b2    = (const float*)d_in[15];
    const float* n2w   = (const float*)d_in[16];
    const float* n2b   = (const float*)d_in[17];
    const float* n2ms  = (const float*)d_in[18];
    const float* fcw   = (const float*)d_in[19];
    const float* fcb   = (const float*)d_in[20];
    float* out = (float*)d_out;

    int N = in_sizes[2];
    int E = in_sizes[1] / 2;
    int Etot = E + N;

    char* ws = (char*)d_ws;
    size_t off = 0;
    auto take = [&](size_t bytes) {
        char* p = ws + off;
        off = (off + bytes + 255) & ~(size_t)255;
        return p;
    };
    unsigned short* WT1b = (unsigned short*)take(128 * 128 * 2);
    unsigned short* WT2b = (unsigned short*)take(128 * 128 * 2);
    float* bc1 = (float*)take(512);
    float* bc2 = (float*)take(512);
    float* ssrc = (float*)take((size_t)N * 16);
    float* sdst = (float*)take((size_t)N * 16);
    int* rowp   = (int*)take((size_t)(N + 1) * 4);
    int* esrc   = (int*)take((size_t)Etot * 4);
    unsigned int* staging = (unsigned int*)take((size_t)Etot * 4);
    int* bbase  = (int*)take(512 * 4);
    int* bcur   = (int*)take(512 * 4);
    unsigned int* H = (unsigned int*)take((size_t)N * 256);  // bf16 [N][128]
    unsigned int* AG = (unsigned int*)take((size_t)N * 256); // bf16 [N][128]
    float* Ac   = (float*)take(64 * 128 * 4);
    float* Bc   = (float*)take(64 * 128 * 4);
    // --- init span: zeros, then 0xFF (rawmin) — single init_kernel ---
    size_t zbeg = off;
    int* bhist   = (int*)take(512 * 4);
    float* gsumA = (float*)take(64 * 128 * 4);
    float* gsqA  = (float*)take(64 * 128 * 4);
    float* gsumB = (float*)take(64 * 128 * 4);
    float* gsqB  = (float*)take(64 * 128 * 4);
    unsigned int* rawmax = (unsigned int*)take(64 * 128 * 4);
    size_t zend = off;
    unsigned int* rawmin = (unsigned int*)take(64 * 128 * 4);  // 0xFF region
    size_t fend = off;
    if (off > ws_size) return;  // workspace too small -> output stays zero

    int nzero = (int)((zend - zbeg) / 4);
    int nff = (int)((fend - zend) / 4);
    int EB = (Etot + 4095) / 4096;
    int SB = (N + 63) / 64;

    init_kernel<<<(nzero + nff + 255) / 256, 256, 0, stream>>>(
        (unsigned int*)(ws + zbeg), nzero, nff);
    prep_weights<<<128, 128, 0, stream>>>(enc_w, enc_b, w1, w2, WT1b, WT2b, bc1, bc2);

    // ---- CSR build (bucketed counting sort) ----
    bucket_hist<<<EB, 256, 0, stream>>>(ei, bhist, E, N);
    bucket_scan<<<1, 512, 0, stream>>>(bhist, bbase, bcur);
    bucket_scatter<<<EB, 256, 0, stream>>>(ei, bcur, staging, E, N);
    bucket_finalize<<<NBUCK, 256, 0, stream>>>(staging, bbase, bcur, rowp, esrc, N, Etot);

    // ---- layer 1 (encoder folded into WT1b/bc1) ----
    gemm_mfma<<<(N + 63) / 64, 256, 0, stream>>>(x, WT1b, bc1, as1, ad1, batch,
                                                 nullptr, nullptr, H, ssrc, sdst, N);
    agg_kernel<<<(N + 3) / 4, 256, 0, stream>>>(rowp, esrc, ssrc, sdst,
                                                (const uint4*)H, b1, (uint4*)AG, N);
    stats_kernel<0><<<SB, 256, 0, stream>>>((const uint4*)AG, batch, gsumA, gsqA,
                                            nullptr, nullptr, N);
    norm_coef<<<64, 128, 0, stream>>>(gsumA, gsqA, batch, N, n1w, n1b, n1ms, Ac, Bc);

    // ---- layer 2 (GraphNorm fused into gemm A-staging; stats+pool one pass) ----
    gemm_mfma<<<(N + 63) / 64, 256, 0, stream>>>(AG, WT2b, bc2, as2, ad2, batch,
                                                 Ac, Bc, H, ssrc, sdst, N);
    agg_kernel<<<(N + 3) / 4, 256, 0, stream>>>(rowp, esrc, ssrc, sdst,
                                                (const uint4*)H, b2, (uint4*)AG, N);
    stats_kernel<1><<<SB, 256, 0, stream>>>((const uint4*)AG, batch, gsumB, gsqB,
                                            rawmax, rawmin, N);
    norm_coef<<<64, 128, 0, stream>>>(gsumB, gsqB, batch, N, n2w, n2b, n2ms, Ac, Bc);

    fc_kernel<<<64, 64, 0, stream>>>(rawmax, rawmin, Ac, Bc, fcw, fcb, out);
}

// Round 9
// 468.549 us; speedup vs baseline: 1.2046x; 1.2046x over previous
//
#include <hip/hip_runtime.h>
#include <hip/hip_bf16.h>

#define SLOPE 0.2f
#define EPS_GN 1e-5f
#define APITCH 136  // LDS row pitch in bf16 elems (272 B): 16B-aligned, breaks power-of-2 bank aliasing
#define NBUCK 391   // ceil(100000/256) dst-buckets of 256 nodes

typedef __attribute__((ext_vector_type(8))) short bfrag;   // 8 bf16 = 4 VGPR (MFMA A/B operand)
typedef __attribute__((ext_vector_type(4))) float ffrag;   // 4 fp32 accumulator

__device__ __forceinline__ float lrelu(float v) { return v > 0.f ? v : SLOPE * v; }
__device__ __forceinline__ short f2bs(float v) {
    __hip_bfloat16 h = __float2bfloat16(v);
    return *reinterpret_cast<short*>(&h);
}
__device__ __forceinline__ float blo(unsigned int u) { return __uint_as_float(u << 16); }
__device__ __forceinline__ float bhi(unsigned int u) { return __uint_as_float(u & 0xffff0000u); }

// ------- weight prep: WT1b[c][k] = bf16((w1@enc_w)[c,k]), bc1 = w1@enc_b ------
__global__ void prep_weights(const float* __restrict__ enc_w,
                             const float* __restrict__ enc_b,
                             const float* __restrict__ w1,
                             const float* __restrict__ w2,
                             unsigned short* __restrict__ WT1b,
                             unsigned short* __restrict__ WT2b,
                             float* __restrict__ bc1, float* __restrict__ bc2) {
    int c = blockIdx.x;   // 128 blocks (output channel)
    int k = threadIdx.x;  // 128 threads (input channel)
    __shared__ float w1row[128];
    w1row[k] = w1[c * 128 + k];
    __syncthreads();
    float acc = 0.f;
    for (int j = 0; j < 128; ++j)
        acc = fmaf(w1row[j], enc_w[j * 128 + k], acc);
    WT1b[c * 128 + k] = (unsigned short)f2bs(acc);
    WT2b[c * 128 + k] = (unsigned short)f2bs(w2[c * 128 + k]);
    if (k == 0) {
        float b = 0.f;
        for (int j = 0; j < 128; ++j) b += w1row[j] * enc_b[j];
        bc1[c] = b;
        bc2[c] = 0.f;
    }
}

// ============ CSR build: two-level bucketed counting sort =====================
// bucket b = dst >> 8 (256 nodes/bucket). Staged word = (src<<8)|(dst&255).

__global__ void __launch_bounds__(256) bucket_hist(const int* __restrict__ ei,
                                                   int* __restrict__ bhist, int E, int N) {
    __shared__ int h[NBUCK];
    for (int i = threadIdx.x; i < NBUCK; i += 256) h[i] = 0;
    __syncthreads();
    int base = blockIdx.x * 4096;
#pragma unroll
    for (int s = 0; s < 16; ++s) {
        int e = base + s * 256 + threadIdx.x;
        if (e < E + N) {
            int dst = (e < E) ? ei[E + e] : (e - E);
            atomicAdd(&h[dst >> 8], 1);
        }
    }
    __syncthreads();
    for (int i = threadIdx.x; i < NBUCK; i += 256)
        if (h[i]) atomicAdd(&bhist[i], h[i]);
}

__global__ void bucket_scan(const int* __restrict__ bhist,
                            int* __restrict__ bbase, int* __restrict__ bcur) {
    __shared__ int sh[512];
    int t = threadIdx.x;  // 512 threads
    int v = (t < NBUCK) ? bhist[t] : 0;
    sh[t] = v;
    __syncthreads();
    for (int off = 1; off < 512; off <<= 1) {
        int add = (t >= off) ? sh[t - off] : 0;
        __syncthreads();
        sh[t] += add;
        __syncthreads();
    }
    if (t < NBUCK) {
        bbase[t] = sh[t] - v;
        bcur[t] = sh[t] - v;
    }
}

__global__ void __launch_bounds__(256) bucket_scatter(const int* __restrict__ ei,
                                                      int* __restrict__ bcur,
                                                      unsigned int* __restrict__ staging,
                                                      int E, int N) {
    __shared__ int h[NBUCK];
    __shared__ int lb[NBUCK];
    for (int i = threadIdx.x; i < NBUCK; i += 256) h[i] = 0;
    __syncthreads();
    int base = blockIdx.x * 4096;
    int srcv[16], dstv[16];
#pragma unroll
    for (int s = 0; s < 16; ++s) {
        int e = base + s * 256 + threadIdx.x;
        srcv[s] = -1;
        if (e < E + N) {
            srcv[s] = (e < E) ? ei[e] : (e - E);
            dstv[s] = (e < E) ? ei[E + e] : (e - E);
            atomicAdd(&h[dstv[s] >> 8], 1);
        }
    }
    __syncthreads();
    for (int i = threadIdx.x; i < NBUCK; i += 256) {
        int c = h[i];
        lb[i] = c ? atomicAdd(&bcur[i], c) : 0;
        h[i] = 0;  // reuse as within-block cursor
    }
    __syncthreads();
#pragma unroll
    for (int s = 0; s < 16; ++s) {
        if (srcv[s] >= 0) {
            int b = dstv[s] >> 8;
            int slot = atomicAdd(&h[b], 1);
            staging[lb[b] + slot] = ((unsigned int)srcv[s] << 8) | (unsigned int)(dstv[s] & 255);
        }
    }
}

// fused: per-bucket degree hist -> LDS exclusive scan -> rowp -> CSR scatter.
__global__ void __launch_bounds__(256) bucket_finalize(
    const unsigned int* __restrict__ staging,
    const int* __restrict__ bbase, const int* __restrict__ bcur,
    int* __restrict__ rowp, int* __restrict__ esrc, int N, int Etot) {
    int b = blockIdx.x, t = threadIdx.x;
    __shared__ int h[256], sc[256];
    h[t] = 0;
    __syncthreads();
    int s0 = bbase[b], s1 = bcur[b];
    for (int j = s0 + t; j < s1; j += 256)
        atomicAdd(&h[staging[j] & 255], 1);
    __syncthreads();
    int d = h[t];
    sc[t] = d;
    __syncthreads();
    for (int off = 1; off < 256; off <<= 1) {
        int add = (t >= off) ? sc[t - off] : 0;
        __syncthreads();
        sc[t] += add;
        __syncthreads();
    }
    int excl = s0 + sc[t] - d;
    int node = b * 256 + t;
    if (node < N) rowp[node] = excl;
    if (b == 0 && t == 0) rowp[N] = Etot;
    __syncthreads();
    h[t] = excl;  // within-bucket cursors
    __syncthreads();
    for (int j = s0 + t; j < s1; j += 256) {
        unsigned int p = staging[j];
        int pos = atomicAdd(&h[p & 255], 1);
        esrc[pos] = (int)(p >> 8);
    }
}

// --------- MFMA GEMM: H[n][128] (bf16) = act(A[n][128]) @ WT^T + bc; + scores --
__global__ void __launch_bounds__(256) gemm_mfma(
    const void* __restrict__ Ain, const unsigned short* __restrict__ WTb,
    const float* __restrict__ bias, const float* __restrict__ att_src,
    const float* __restrict__ att_dst, const int* __restrict__ batch,
    const float* __restrict__ Ac, const float* __restrict__ Bc,
    unsigned int* __restrict__ H, float* __restrict__ ssrc, float* __restrict__ sdst, int N) {
    __shared__ short Bsh[128 * APITCH];  // [c][k] bf16
    __shared__ short Ash[64 * APITCH];   // [node][k] bf16 (reused for C)
    __shared__ float asrc_s[128], adst_s[128], bias_s[128];
    int tid = threadIdx.x;
    int base = blockIdx.x * 64;

    for (int idx = tid; idx < 2048; idx += 256) {
        int c = idx >> 4, k8 = (idx & 15) * 8;
        uint4 wv = ((const uint4*)WTb)[idx];
        *(uint4*)&Bsh[c * APITCH + k8] = wv;
    }
    if (Ac == nullptr) {
        const float* A = (const float*)Ain;
        for (int idx = tid; idx < 2048; idx += 256) {
            int nl = idx >> 5, k4 = (idx & 31) * 4;
            int node = base + nl;
            float4 v = make_float4(0.f, 0.f, 0.f, 0.f);
            if (node < N) v = ((const float4*)A)[node * 32 + (idx & 31)];
            *(short4*)&Ash[nl * APITCH + k4] =
                make_short4(f2bs(v.x), f2bs(v.y), f2bs(v.z), f2bs(v.w));
        }
    } else {
        const uint4* A4 = (const uint4*)Ain;
        for (int idx = tid; idx < 1024; idx += 256) {
            int nl = idx >> 4, u4 = idx & 15, k8 = u4 * 8;
            int node = base + nl;
            short o[8] = {0, 0, 0, 0, 0, 0, 0, 0};
            if (node < N) {
                uint4 hb = A4[node * 16 + u4];
                int g = batch[node];
                float4 a0 = *(const float4*)&Ac[g * 128 + k8];
                float4 a1 = *(const float4*)&Ac[g * 128 + k8 + 4];
                float4 b0 = *(const float4*)&Bc[g * 128 + k8];
                float4 b1 = *(const float4*)&Bc[g * 128 + k8 + 4];
                o[0] = f2bs(fmaf(blo(hb.x), a0.x, b0.x));
                o[1] = f2bs(fmaf(bhi(hb.x), a0.y, b0.y));
                o[2] = f2bs(fmaf(blo(hb.y), a0.z, b0.z));
                o[3] = f2bs(fmaf(bhi(hb.y), a0.w, b0.w));
                o[4] = f2bs(fmaf(blo(hb.z), a1.x, b1.x));
                o[5] = f2bs(fmaf(bhi(hb.z), a1.y, b1.y));
                o[6] = f2bs(fmaf(blo(hb.w), a1.z, b1.z));
                o[7] = f2bs(fmaf(bhi(hb.w), a1.w, b1.w));
            }
            *(bfrag*)&Ash[nl * APITCH + k8] = *(bfrag*)o;
        }
    }
    if (tid < 128) {
        asrc_s[tid] = att_src[tid];
        adst_s[tid] = att_dst[tid];
        bias_s[tid] = bias[tid];
    }
    __syncthreads();

    int w = tid >> 6, lane = tid & 63, col = lane & 15, quad = lane >> 4;
    int rowBase = w * 16;

    bfrag afr[4];
#pragma unroll
    for (int s = 0; s < 4; ++s)
        afr[s] = *(const bfrag*)&Ash[(rowBase + col) * APITCH + s * 32 + quad * 8];

    ffrag acc[8];
#pragma unroll
    for (int t = 0; t < 8; ++t) acc[t] = (ffrag){0.f, 0.f, 0.f, 0.f};

#pragma unroll
    for (int t = 0; t < 8; ++t) {
#pragma unroll
        for (int s = 0; s < 4; ++s) {
            bfrag bfr = *(const bfrag*)&Bsh[(t * 16 + col) * APITCH + s * 32 + quad * 8];
            acc[t] = __builtin_amdgcn_mfma_f32_16x16x32_bf16(afr[s], bfr, acc[t], 0, 0, 0);
        }
    }

#pragma unroll
    for (int t = 0; t < 8; ++t) {
        int ch = t * 16 + col;
        float bv = bias_s[ch];
#pragma unroll
        for (int r = 0; r < 4; ++r)
            Ash[(rowBase + quad * 4 + r) * APITCH + ch] = f2bs(acc[t][r] + bv);
    }
    __syncthreads();

    float2 av = make_float2(asrc_s[lane * 2], asrc_s[lane * 2 + 1]);
    float2 dv = make_float2(adst_s[lane * 2], adst_s[lane * 2 + 1]);
    for (int r = 0; r < 16; ++r) {
        int node = base + rowBase + r;
        unsigned int hb = *(const unsigned int*)&Ash[(rowBase + r) * APITCH + lane * 2];
        float hx = blo(hb);
        float hy = bhi(hb);
        float vs = hx * av.x + hy * av.y;
        float vd = hx * dv.x + hy * dv.y;
#pragma unroll
        for (int off = 8; off; off >>= 1) {
            vs += __shfl_xor(vs, off, 16);
            vd += __shfl_xor(vd, off, 16);
        }
        if (node < N) {
            H[node * 64 + lane] = hb;
            if ((lane & 15) == 0) {
                int h = lane >> 4;
                ssrc[node * 4 + h] = vs;
                sdst[node * 4 + h] = vd;
            }
        }
    }
}

// ------- aggregation: single-pass softmax num+den; ONE WAVE PER NODE ----------
// (round-5 form: max MLP across 100k waves; fusion attempts regress — R7)
__global__ void __launch_bounds__(256) agg_kernel(
    const int* __restrict__ row, const int* __restrict__ esrc,
    const float* __restrict__ ssrc, const float* __restrict__ sdst,
    const uint4* __restrict__ H4, const float* __restrict__ bias,
    uint4* __restrict__ out, int N) {
    int n = (blockIdx.x * 256 + threadIdx.x) >> 6;
    int lane = threadIdx.x & 63;
    if (n >= N) return;
    int slot = lane >> 4, li = lane & 15, head = li >> 2;
    int beg = row[n], end = row[n + 1];
    float sdh = sdst[n * 4 + head];

    float num[8] = {0.f, 0.f, 0.f, 0.f, 0.f, 0.f, 0.f, 0.f};
    float den = 0.f;
    for (int e = beg + slot; e < end; e += 4) {
        int s = esrc[e];
        float al = __expf(lrelu(ssrc[s * 4 + head] + sdh));
        uint4 hb = H4[s * 16 + li];
        den += al;
        num[0] = fmaf(al, blo(hb.x), num[0]);
        num[1] = fmaf(al, bhi(hb.x), num[1]);
        num[2] = fmaf(al, blo(hb.y), num[2]);
        num[3] = fmaf(al, bhi(hb.y), num[3]);
        num[4] = fmaf(al, blo(hb.z), num[4]);
        num[5] = fmaf(al, bhi(hb.z), num[5]);
        num[6] = fmaf(al, blo(hb.w), num[6]);
        num[7] = fmaf(al, bhi(hb.w), num[7]);
    }
    den += __shfl_xor(den, 16);
    den += __shfl_xor(den, 32);
#pragma unroll
    for (int j = 0; j < 8; ++j) {
        num[j] += __shfl_xor(num[j], 16);
        num[j] += __shfl_xor(num[j], 32);
    }
    if (slot == 0) {
        float rh = 1.f / den;
        int c0 = li * 8;
        unsigned int o[4];
#pragma unroll
        for (int p = 0; p < 4; ++p) {
            float v0 = fmaf(num[2 * p], rh, bias[c0 + 2 * p]);
            float v1 = fmaf(num[2 * p + 1], rh, bias[c0 + 2 * p + 1]);
            v0 = v0 > 0.f ? v0 : __expf(v0) - 1.f;  // ELU
            v1 = v1 > 0.f ? v1 : __expf(v1) - 1.f;
            o[p] = ((unsigned int)(unsigned short)f2bs(v0)) |
                   (((unsigned int)(unsigned short)f2bs(v1)) << 16);
        }
        out[n * 16 + li] = make_uint4(o[0], o[1], o[2], o[3]);
    }
}

// ------- GraphNorm stats (+ max/min for layer 2) — ATOMIC-FREE ----------------
// Stage 1: per-block partials via plain coalesced stores. part[b][q][128],
// q: 0=sum(set0) 1=sq(set0) 2=sum(set1) 3=sq(set1) 4=mx0 5=mn0 6=mx1 7=mn1.
// set1 = rows whose group != batch[block_base] (<=2 groups per 64-row window).
template <int POOL>
__global__ void __launch_bounds__(256) stats_kernel(
    const uint4* __restrict__ X4, const int* __restrict__ batch,
    float* __restrict__ part, int N) {
    __shared__ float red[16][16][9];  // [rowgroup][u4][ch(+pad)]
    int t = threadIdx.x, u4 = t & 15, rg = t >> 4;
    int base = blockIdx.x * 64;
    int g0 = batch[base];

    float s[2][8] = {}, q[2][8] = {};
    float mx[2][8], mn[2][8];
#pragma unroll
    for (int st = 0; st < 2; ++st)
#pragma unroll
        for (int p = 0; p < 8; ++p) { mx[st][p] = -3e38f; mn[st][p] = 3e38f; }

#pragma unroll
    for (int rr = 0; rr < 4; ++rr) {
        int node = base + rg + rr * 16;
        if (node < N) {
            uint4 hb = X4[node * 16 + u4];
            int st = (batch[node] != g0) ? 1 : 0;
            float vv[8] = {blo(hb.x), bhi(hb.x), blo(hb.y), bhi(hb.y),
                           blo(hb.z), bhi(hb.z), blo(hb.w), bhi(hb.w)};
#pragma unroll
            for (int p = 0; p < 8; ++p) {
                s[st][p] += vv[p];
                q[st][p] += vv[p] * vv[p];
                if (POOL) {
                    mx[st][p] = fmaxf(mx[st][p], vv[p]);
                    mn[st][p] = fminf(mn[st][p], vv[p]);
                }
            }
        }
    }

    int uu = t >> 3, ch = t & 7;  // reducer mapping (threads 0..127 -> channel t)
    float rs[2] = {0.f, 0.f}, rq[2] = {0.f, 0.f};
    float rmx[2] = {-3e38f, -3e38f}, rmn[2] = {3e38f, 3e38f};
    for (int st = 0; st < 2; ++st) {
#pragma unroll
        for (int p = 0; p < 8; ++p) red[rg][u4][p] = s[st][p];
        __syncthreads();
        if (t < 128) { float a = 0.f; for (int r2 = 0; r2 < 16; ++r2) a += red[r2][uu][ch]; rs[st] = a; }
        __syncthreads();
#pragma unroll
        for (int p = 0; p < 8; ++p) red[rg][u4][p] = q[st][p];
        __syncthreads();
        if (t < 128) { float a = 0.f; for (int r2 = 0; r2 < 16; ++r2) a += red[r2][uu][ch]; rq[st] = a; }
        __syncthreads();
        if (POOL) {
#pragma unroll
            for (int p = 0; p < 8; ++p) red[rg][u4][p] = mx[st][p];
            __syncthreads();
            if (t < 128) { float a = -3e38f; for (int r2 = 0; r2 < 16; ++r2) a = fmaxf(a, red[r2][uu][ch]); rmx[st] = a; }
            __syncthreads();
#pragma unroll
            for (int p = 0; p < 8; ++p) red[rg][u4][p] = mn[st][p];
            __syncthreads();
            if (t < 128) { float a = 3e38f; for (int r2 = 0; r2 < 16; ++r2) a = fminf(a, red[r2][uu][ch]); rmn[st] = a; }
            __syncthreads();
        }
    }
    if (t < 128) {
        float* pb = part + (size_t)blockIdx.x * 8 * 128;
        pb[0 * 128 + t] = rs[0];
        pb[1 * 128 + t] = rq[0];
        pb[2 * 128 + t] = rs[1];
        pb[3 * 128 + t] = rq[1];
        if (POOL) {
            pb[4 * 128 + t] = rmx[0];
            pb[5 * 128 + t] = rmn[0];
            pb[6 * 128 + t] = rmx[1];
            pb[7 * 128 + t] = rmn[1];
        }
    }
}

// Stage 2: per-group gather of block partials -> GraphNorm coefficients.
// POOL=0: write Ac/Bc (consumed by gemm2's fused normalize).
// POOL=1: write pooled[g][c] = Ac>=0 ? Ac*max+Bc : Ac*min+Bc (monotone affine).
template <int POOL>
__global__ void reduce_coef(const float* __restrict__ part,
                            const int* __restrict__ batch, int N,
                            const float* __restrict__ w, const float* __restrict__ b,
                            const float* __restrict__ ms,
                            float* __restrict__ Ac, float* __restrict__ Bc,
                            float* __restrict__ pooled) {
    __shared__ int sh2[2];
    int g = blockIdx.x, c = threadIdx.x;  // 64 x 128
    if (c < 2) {
        int key = g + c;  // lower_bound(batch, key)
        int lo = 0, hi = N;
        while (lo < hi) { int m = (lo + hi) >> 1; if (batch[m] < key) lo = m + 1; else hi = m; }
        sh2[c] = lo;
    }
    __syncthreads();
    int sidx = sh2[0], eidx = sh2[1];
    float cnt = (float)(eidx - sidx);
    if (cnt < 0.5f) {
        if (POOL) pooled[g * 128 + c] = 0.f;
        else { Ac[g * 128 + c] = 0.f; Bc[g * 128 + c] = 0.f; }
        return;
    }
    int b0 = sidx >> 6, b1 = (eidx - 1) >> 6;
    float s = 0.f, q = 0.f, M = -3e38f, m = 3e38f;
    for (int bb = b0; bb <= b1; ++bb) {
        int g0b = batch[bb << 6];
        int qoff;
        bool take;
        if (g0b == g) { qoff = 0; take = true; }
        else {
            int g1b = batch[min((bb << 6) + 63, N - 1)];
            take = (g1b == g);
            qoff = 2;
        }
        if (take) {
            const float* pb = part + (size_t)bb * 8 * 128;
            s += pb[qoff * 128 + c];
            q += pb[(qoff + 1) * 128 + c];
            if (POOL) {
                M = fmaxf(M, pb[(4 + qoff) * 128 + c]);
                m = fminf(m, pb[(5 + qoff) * 128 + c]);
            }
        }
    }
    float mean = s / cnt;
    float msv = ms[c];
    float var = q / cnt - msv * (2.f - msv) * mean * mean;
    var = fmaxf(var, 0.f);
    float inv = rsqrtf(var + EPS_GN);
    float a = w[c] * inv;
    float bb2 = b[c] - msv * mean * a;
    if (POOL) pooled[g * 128 + c] = (a >= 0.f) ? fmaf(a, M, bb2) : fmaf(a, m, bb2);
    else { Ac[g * 128 + c] = a; Bc[g * 128 + c] = bb2; }
}

// ---------------- FC: out[g][o] = pooled[g] . fc_w[o] + fc_b[o] --------------
__global__ void fc_kernel(const float* __restrict__ pooled,
                          const float* __restrict__ fcw,
                          const float* __restrict__ fcb,
                          float* __restrict__ out) {
    int g = blockIdx.x, o = threadIdx.x;  // 64 x 64
    __shared__ float p[128];
    p[o] = pooled[g * 128 + o];
    p[o + 64] = pooled[g * 128 + 64 + o];
    __syncthreads();
    float acc = fcb[o];
    for (int k = 0; k < 128; ++k)
        acc = fmaf(p[k], fcw[o * 128 + k], acc);
    out[g * 64 + o] = acc;
}

extern "C" void kernel_launch(void* const* d_in, const int* in_sizes, int n_in,
                              void* d_out, int out_size, void* d_ws, size_t ws_size,
                              hipStream_t stream) {
    const float* x     = (const float*)d_in[0];
    const int* ei      = (const int*)d_in[1];
    const int* batch   = (const int*)d_in[2];
    const float* enc_w = (const float*)d_in[3];
    const float* enc_b = (const float*)d_in[4];
    const float* w1    = (const float*)d_in[5];
    const float* as1   = (const float*)d_in[6];
    const float* ad1   = (const float*)d_in[7];
    const float* b1    = (const float*)d_in[8];
    const float* n1w   = (const float*)d_in[9];
    const float* n1b   = (const float*)d_in[10];
    const float* n1ms  = (const float*)d_in[11];
    const float* w2    = (const float*)d_in[12];
    const float* as2   = (const float*)d_in[13];
    const float* ad2   = (const float*)d_in[14];
    const float* b2    = (const float*)d_in[15];
    const float* n2w   = (const float*)d_in[16];
    const float* n2b   = (const float*)d_in[17];
    const float* n2ms  = (const float*)d_in[18];
    const float* fcw   = (const float*)d_in[19];
    const float* fcb   = (const float*)d_in[20];
    float* out = (float*)d_out;

    int N = in_sizes[2];
    int E = in_sizes[1] / 2;
    int Etot = E + N;
    int SB = (N + 63) / 64;

    char* ws = (char*)d_ws;
    size_t off = 0;
    auto take = [&](size_t bytes) {
        char* p = ws + off;
        off = (off + bytes + 255) & ~(size_t)255;
        return p;
    };
    unsigned short* WT1b = (unsigned short*)take(128 * 128 * 2);
    unsigned short* WT2b = (unsigned short*)take(128 * 128 * 2);
    float* bc1 = (float*)take(512);
    float* bc2 = (float*)take(512);
    float* ssrc = (float*)take((size_t)N * 16);
    float* sdst = (float*)take((size_t)N * 16);
    int* rowp   = (int*)take((size_t)(N + 1) * 4);
    int* esrc   = (int*)take((size_t)Etot * 4);
    unsigned int* staging = (unsigned int*)take((size_t)Etot * 4);
    int* bbase  = (int*)take(512 * 4);
    int* bcur   = (int*)take(512 * 4);
    int* bhist  = (int*)take(512 * 4);
    unsigned int* H = (unsigned int*)take((size_t)N * 256);  // bf16 [N][128]
    unsigned int* AG = (unsigned int*)take((size_t)N * 256); // bf16 [N][128]
    float* Ac   = (float*)take(64 * 128 * 4);
    float* Bc   = (float*)take(64 * 128 * 4);
    float* part = (float*)take((size_t)SB * 8 * 128 * 4);    // per-block partials
    float* pooled = (float*)take(64 * 128 * 4);
    if (off > ws_size) return;  // workspace too small -> output stays zero

    int EB = (Etot + 4095) / 4096;

    hipMemsetAsync(bhist, 0, 512 * 4, stream);
    prep_weights<<<128, 128, 0, stream>>>(enc_w, enc_b, w1, w2, WT1b, WT2b, bc1, bc2);

    // ---- CSR build (bucketed counting sort) ----
    bucket_hist<<<EB, 256, 0, stream>>>(ei, bhist, E, N);
    bucket_scan<<<1, 512, 0, stream>>>(bhist, bbase, bcur);
    bucket_scatter<<<EB, 256, 0, stream>>>(ei, bcur, staging, E, N);
    bucket_finalize<<<NBUCK, 256, 0, stream>>>(staging, bbase, bcur, rowp, esrc, N, Etot);

    // ---- layer 1 (encoder folded into WT1b/bc1) ----
    gemm_mfma<<<(N + 63) / 64, 256, 0, stream>>>(x, WT1b, bc1, as1, ad1, batch,
                                                 nullptr, nullptr, H, ssrc, sdst, N);
    agg_kernel<<<(N + 3) / 4, 256, 0, stream>>>(rowp, esrc, ssrc, sdst,
                                                (const uint4*)H, b1, (uint4*)AG, N);
    stats_kernel<0><<<SB, 256, 0, stream>>>((const uint4*)AG, batch, part, N);
    reduce_coef<0><<<64, 128, 0, stream>>>(part, batch, N, n1w, n1b, n1ms, Ac, Bc, nullptr);

    // ---- layer 2 (GraphNorm fused into gemm A-staging; stats+pool one pass) ----
    gemm_mfma<<<(N + 63) / 64, 256, 0, stream>>>(AG, WT2b, bc2, as2, ad2, batch,
                                                 Ac, Bc, H, ssrc, sdst, N);
    agg_kernel<<<(N + 3) / 4, 256, 0, stream>>>(rowp, esrc, ssrc, sdst,
                                                (const uint4*)H, b2, (uint4*)AG, N);
    stats_kernel<1><<<SB, 256, 0, stream>>>((const uint4*)AG, batch, part, N);
    reduce_coef<1><<<64, 128, 0, stream>>>(part, batch, N, n2w, n2b, n2ms,
                                           nullptr, nullptr, pooled);

    fc_kernel<<<64, 64, 0, stream>>>(pooled, fcw, fcb, out);
}